// Round 2
// baseline (9.387 us; speedup 1.0000x reference)
//
#include <hip/hip_runtime.h>

static constexpr int J  = 17;
static constexpr int NH = 30;

// One wave (64 lanes) per batch element:
//   lanes  0..29 -> humans 0..29 of map0 (256x256)
//   lanes 32..61 -> humans 0..29 of map1 (512x512)
// No LDS, no barriers: avg sharing + reductions via in-wave shuffles.
__global__ __launch_bounds__(64) void ae_loss_kernel(
    const float* __restrict__ tm0,   // (B, J, 256, 256)
    const float* __restrict__ tm1,   // (B, J, 512, 512)
    const int*   __restrict__ kps0,  // (B, NH, 3*J)
    const int*   __restrict__ kps1,  // (B, NH, 3*J)
    float*       __restrict__ out)   // (B,)
{
    const int b    = blockIdx.x;
    const int lane = threadIdx.x;        // 0..63
    const int half = lane >> 5;          // 0 -> map0, 1 -> map1
    const int hl   = lane & 31;          // human index within half

    const int    res  = half ? 512 : 256;
    const float* tmap = half ? (tm1 + (size_t)b * J * 512 * 512)
                             : (tm0 + (size_t)b * J * 256 * 256);
    const int*   kps  = (half ? kps1 : kps0) + b * NH * 3 * J;

    float    vals[J];
    unsigned mbits = 0;
    float    avg   = 0.f;
    int      cnt   = 0;

    if (hl < NH) {
        const int* k = kps + hl * 3 * J;
        float sum = 0.f;
        #pragma unroll
        for (int j = 0; j < J; ++j) {
            const int x = k[3 * j + 0];
            const int y = k[3 * j + 1];
            const int v = k[3 * j + 2];
            const float val = tmap[((size_t)j * res + x) * res + y];
            vals[j] = val;
            if (v != 0) { mbits |= (1u << j); cnt++; sum += val; }
        }
        avg = (cnt > 0) ? (sum / (float)cnt) : 0.f;
    }

    // pull term (per human)
    float pull_h = 0.f;
    #pragma unroll
    for (int j = 0; j < J; ++j) {
        if (mbits & (1u << j)) {
            const float d = vals[j] - avg;
            pull_h = fmaf(d, d, pull_h);
        }
    }

    // push term: all-pairs within this half's 30 avgs via in-wave broadcast
    float push_row = 0.f;
    const int base = half << 5;
    #pragma unroll
    for (int m = 0; m < NH; ++m) {
        const float am = __shfl(avg, base + m);   // uniform-within-half src lane
        const float d  = avg - am;
        push_row += __expf(-0.5f * d * d);
    }
    if (hl >= NH) { pull_h = 0.f; push_row = 0.f; }
    const float nh = (hl < NH && cnt > 0) ? 1.f : 0.f;

    // width-32 reductions (each half independently; lanes >=30 hold zeros)
    float psum = pull_h, qsum = push_row, nsum = nh;
    #pragma unroll
    for (int off = 16; off > 0; off >>= 1) {
        psum += __shfl_down(psum, off, 32);
        qsum += __shfl_down(qsum, off, 32);
        nsum += __shfl_down(nsum, off, 32);
    }

    // per-half loss at hl==0 (lanes 0 and 32); reference divides unguarded
    const float inv = 1.f / nsum;
    const float s   = fmaf(qsum * inv, inv, psum * inv);

    const float s_other = __shfl(s, 32);
    if (lane == 0) out[b] = s + s_other;
}

extern "C" void kernel_launch(void* const* d_in, const int* in_sizes, int n_in,
                              void* d_out, int out_size, void* d_ws, size_t ws_size,
                              hipStream_t stream) {
    const float* tm0  = (const float*)d_in[0];
    const float* tm1  = (const float*)d_in[1];
    const int*   kps0 = (const int*)d_in[2];
    const int*   kps1 = (const int*)d_in[3];
    float*       out  = (float*)d_out;

    const int B = in_sizes[2] / (NH * 3 * J);   // 8
    ae_loss_kernel<<<B, 64, 0, stream>>>(tm0, tm1, kps0, kps1, out);
}